// Round 8
// baseline (292.581 us; speedup 1.0000x reference)
//
#include <hip/hip_runtime.h>
#include <hip/hip_bf16.h>
#include <cstdint>
#include <cstddef>

// B=4, S=2048, D=1024, H=16, DH=64.  BS = 8192 rows.
// pack_all: W transposes via LDS (coalesced), x->bf16, bias pack
// gemm_qkv: QK[8192][2048] bf16 (Q pre-scaled 0.125*log2e, bias folded);
//           V-blocks (n0>=2048) write TRANSPOSED directly to Vtg[bh][e][s]
// attn: flash, S^T trick, exp2 domain, l-via-MFMA -> MH [8192][1024] bf16
// gemm_out: 64x128 tiles, out[8192][1024] f32 = MH @ Wo^T + bo

typedef unsigned short u16;
typedef unsigned int u32;
typedef __attribute__((ext_vector_type(8))) __bf16 bf16x8;
typedef __attribute__((ext_vector_type(8))) unsigned short u16x8;
typedef __attribute__((ext_vector_type(4))) float f32x4;
typedef __attribute__((ext_vector_type(4))) unsigned int u32x4;

__device__ __forceinline__ u16 f2bf(float f) {
  union { __hip_bfloat16 h; u16 u; } c;
  c.h = __float2bfloat16(f);
  return c.u;
}
// 3-op bf16x2 pack (round-half-up; p>0 always so carry is exact):
// two v_add + one v_perm_b32 selecting the high halves.
// low16 = bf16(a), high16 = bf16(b).
__device__ __forceinline__ u32 pk2fast(float a, float b) {
  const u32 ra = __float_as_uint(a) + 0x8000u;
  const u32 rb = __float_as_uint(b) + 0x8000u;
  return __builtin_amdgcn_perm(rb, ra, 0x07060302u);
}
// exp2 via the amdgcn builtin (v_exp_f32). NOTE: __exp2f collides with a
// glibc math.h macro in this env — do not use it.
__device__ __forceinline__ float ex2(float x) {
  return __builtin_amdgcn_exp2f(x);
}

// async 16B global->LDS; LDS dest is wave-uniform base + lane*16.
__device__ __forceinline__ void async16(const void* g, void* l) {
  __builtin_amdgcn_global_load_lds(
      (const __attribute__((address_space(1))) void*)g,
      (__attribute__((address_space(3))) void*)l, 16, 0, 0);
}

// --------------------------------------------------------- merged packs ----
// grid [0,1024): 64x64 f32->bf16 LDS transposes (768 Wqkv + 256 Wo),
//   coalesced reads+writes. [1024,9216): x->bf16 | [9216,9228): bias pack.
__global__ void k_pack_all(const float* __restrict__ x,
                           const float* __restrict__ Wq, const float* __restrict__ Wk,
                           const float* __restrict__ Wv,
                           const float* __restrict__ bq, const float* __restrict__ bk,
                           const float* __restrict__ bv,
                           const float* __restrict__ Wo,
                           u16* __restrict__ xb, u16* __restrict__ Wt,
                           float* __restrict__ bqkv, u16* __restrict__ Wot) {
  __shared__ __align__(16) u16 tile[64][72];
  const int bid = blockIdx.x;
  const int t = threadIdx.x;
  if (bid < 1024) {
    const float* src;
    u16* dstp;
    int rstride, n_base, d0;
    if (bid < 768) {     // Wt[proj*1024+h*64+e][d] = Wp[h][d][e]
      const int proj = bid >> 8, h = (bid >> 4) & 15, dt = bid & 15;
      const float* Wp = (proj == 0) ? Wq : ((proj == 1) ? Wk : Wv);
      src = Wp + h * 65536 + (dt * 64) * 64;
      rstride = 64;
      n_base = proj * 1024 + h * 64;
      d0 = dt * 64;
      dstp = Wt;
    } else {             // Wot[n][d] = Wo[d][n]
      const int tb = bid - 768, nt = tb >> 4, dt = tb & 15;
      src = Wo + (size_t)(dt * 64) * 1024 + nt * 64;
      rstride = 1024;
      n_base = nt * 64;
      d0 = dt * 64;
      dstp = Wot;
    }
    {
      const int row = t >> 2, c0 = (t & 3) * 16;
      const float* s = src + row * rstride + c0;
#pragma unroll
      for (int j = 0; j < 4; ++j) {
        const float4 v = *(const float4*)(s + j * 4);
        ushort4 o;
        o.x = f2bf(v.x); o.y = f2bf(v.y); o.z = f2bf(v.z); o.w = f2bf(v.w);
        *(ushort4*)&tile[row][c0 + j * 4] = o;
      }
    }
    __syncthreads();
    {
      const int e = t >> 2, c0 = (t & 3) * 16;
      u16 buf[16];
#pragma unroll
      for (int i = 0; i < 16; ++i) buf[i] = tile[c0 + i][e];
      u16* d = dstp + (size_t)(n_base + e) * 1024 + d0 + c0;
      *(u16x8*)d = *(const u16x8*)&buf[0];
      *(u16x8*)(d + 8) = *(const u16x8*)&buf[8];
    }
  } else if (bid < 9216) {
    const int i = ((bid - 1024) * 256 + t) * 4;
    const float4 v = *(const float4*)(x + i);
    ushort4 o;
    o.x = f2bf(v.x); o.y = f2bf(v.y); o.z = f2bf(v.z); o.w = f2bf(v.w);
    *(ushort4*)(xb + i) = o;
  } else {
    const int n = (bid - 9216) * 256 + t;
    const int proj = n >> 10, rem = n & 1023, h = rem >> 6, e = rem & 63;
    const float* bp = (proj == 0) ? bq : ((proj == 1) ? bk : bv);
    bqkv[n] = bp[h * 64 + e];
  }
}

// --------------------------------------------------------------- GEMM qkv --
// 128x128 tile, m97 structure. MODE 0 (qkv): N=3072 logical; Q cols scaled
// by 0.125*log2e; Q/K blocks (n0<2048) -> Cout bf16 ldc=2048; V blocks
// (n0>=2048) write TRANSPOSED to vtg[bh][e][s] (C-layout gives 4 contiguous
// s per lane -> 8B stores). MODE 1: f32 out + bias (unused here; kept).
template <int MODE>
__global__ __launch_bounds__(256)
void k_gemm(const u16* __restrict__ A, const u16* __restrict__ Bt,
            const float* __restrict__ bias, void* __restrict__ Cout, int ldc,
            u16* __restrict__ vtg) {
  __shared__ __align__(16) u16 Alds[128 * 32];
  __shared__ __align__(16) u16 Blds[128 * 32];
  const int t = threadIdx.x;
  const int lane = t & 63;
  const int w = t >> 6;
  const int l15 = lane & 15;
  const int quad = lane >> 4;
  const int wm = w >> 1, wn = w & 1;
  const int m0 = blockIdx.y << 7;
  const int n0 = blockIdx.x << 7;

  const u16* ga0 = A + (size_t)(m0 + (t >> 2)) * 1024 + (t & 3) * 8;
  const u16* ga1 = ga0 + (size_t)64 * 1024;
  const u16* gb0 = Bt + (size_t)(n0 + (t >> 2)) * 1024 + (t & 3) * 8;
  const u16* gb1 = gb0 + (size_t)64 * 1024;
  u16* const lA0 = Alds + w * 512;
  u16* const lA1 = Alds + w * 512 + 2048;
  u16* const lB0 = Blds + w * 512;
  u16* const lB1 = Blds + w * 512 + 2048;

  f32x4 acc[4][4];
#pragma unroll
  for (int mi = 0; mi < 4; ++mi)
#pragma unroll
    for (int ni = 0; ni < 4; ++ni) acc[mi][ni] = (f32x4){0.f, 0.f, 0.f, 0.f};

  for (int k0 = 0; k0 < 1024; k0 += 32) {
    __syncthreads();
    async16(ga0, lA0); async16(ga1, lA1);
    async16(gb0, lB0); async16(gb1, lB1);
    ga0 += 32; ga1 += 32; gb0 += 32; gb1 += 32;
    __syncthreads();
    bf16x8 af[4], bfr[4];
#pragma unroll
    for (int i = 0; i < 4; ++i) {
      af[i]  = *(const bf16x8*)(Alds + (wm * 64 + i * 16 + l15) * 32 + quad * 8);
      bfr[i] = *(const bf16x8*)(Blds + (wn * 64 + i * 16 + l15) * 32 + quad * 8);
    }
#pragma unroll
    for (int mi = 0; mi < 4; ++mi)
#pragma unroll
      for (int ni = 0; ni < 4; ++ni)
        acc[mi][ni] = __builtin_amdgcn_mfma_f32_16x16x32_bf16(af[mi], bfr[ni], acc[mi][ni], 0, 0, 0);
  }

  const int row0 = m0 + wm * 64;
  const int col0 = n0 + wn * 64;
  if (MODE == 0 && n0 >= 2048) {
    // V block -> Vtg[bh][e][s]; s = row&2047 contiguous over reg idx r.
    const int bq_ = row0 >> 11;
    const int sb = row0 & 2047;
#pragma unroll
    for (int mi = 0; mi < 4; ++mi) {
#pragma unroll
      for (int ni = 0; ni < 4; ++ni) {
        const int col = col0 + ni * 16 + l15;
        const float bb = bias[col];
        const int vcol = col - 2048;
        u16* dst = vtg + ((size_t)((bq_ * 16 + (vcol >> 6)) * 64 + (vcol & 63))) * 2048
                       + sb + mi * 16 + quad * 4;
        uint2 pr;
        pr.x = (u32)f2bf(acc[mi][ni][0] + bb) | ((u32)f2bf(acc[mi][ni][1] + bb) << 16);
        pr.y = (u32)f2bf(acc[mi][ni][2] + bb) | ((u32)f2bf(acc[mi][ni][3] + bb) << 16);
        *(uint2*)dst = pr;
      }
    }
  } else {
    // Q prescale: 1/sqrt(64)*log2(e) so attention uses bare v_exp_f32 (exp2)
    const float qscale = (MODE == 0 && col0 < 1024) ? 0.125f * 1.4426950408889634f : 1.0f;
#pragma unroll
    for (int mi = 0; mi < 4; ++mi) {
#pragma unroll
      for (int ni = 0; ni < 4; ++ni) {
        const int col = col0 + ni * 16 + l15;
        const float bb = bias[col];
#pragma unroll
        for (int r = 0; r < 4; ++r) {
          const int row = row0 + mi * 16 + quad * 4 + r;
          const float v = (acc[mi][ni][r] + bb) * qscale;
          if (MODE == 0) ((u16*)Cout)[(size_t)row * ldc + col] = f2bf(v);
          else           ((float*)Cout)[(size_t)row * ldc + col] = v;
        }
      }
    }
  }
}

// --------------------------------------------------------------- GEMM out --
// 64x128 tile -> grid (8,128) = 1024 blocks = 4/CU (128x128 gave only 2/CU
// on N=1024 and was latency-exposed). 4 waves in 2x2, each 32x64.
__global__ __launch_bounds__(256)
void k_gemm_out(const u16* __restrict__ A, const u16* __restrict__ Bt,
                const float* __restrict__ bias, float* __restrict__ Cout) {
  __shared__ __align__(16) u16 Alds[64 * 32];
  __shared__ __align__(16) u16 Blds[128 * 32];
  const int t = threadIdx.x;
  const int lane = t & 63;
  const int w = t >> 6;
  const int l15 = lane & 15;
  const int quad = lane >> 4;
  const int wm = w >> 1, wn = w & 1;
  const int m0 = blockIdx.y << 6;
  const int n0 = blockIdx.x << 7;

  const u16* ga  = A + (size_t)(m0 + (t >> 2)) * 1024 + (t & 3) * 8;
  const u16* gb0 = Bt + (size_t)(n0 + (t >> 2)) * 1024 + (t & 3) * 8;
  const u16* gb1 = gb0 + (size_t)64 * 1024;
  u16* const lA  = Alds + w * 512;
  u16* const lB0 = Blds + w * 512;
  u16* const lB1 = Blds + w * 512 + 2048;

  f32x4 acc[2][4];
#pragma unroll
  for (int mi = 0; mi < 2; ++mi)
#pragma unroll
    for (int ni = 0; ni < 4; ++ni) acc[mi][ni] = (f32x4){0.f, 0.f, 0.f, 0.f};

  for (int k0 = 0; k0 < 1024; k0 += 32) {
    __syncthreads();
    async16(ga, lA); async16(gb0, lB0); async16(gb1, lB1);
    ga += 32; gb0 += 32; gb1 += 32;
    __syncthreads();
    bf16x8 af[2], bfr[4];
#pragma unroll
    for (int i = 0; i < 2; ++i)
      af[i]  = *(const bf16x8*)(Alds + (wm * 32 + i * 16 + l15) * 32 + quad * 8);
#pragma unroll
    for (int i = 0; i < 4; ++i)
      bfr[i] = *(const bf16x8*)(Blds + (wn * 64 + i * 16 + l15) * 32 + quad * 8);
#pragma unroll
    for (int mi = 0; mi < 2; ++mi)
#pragma unroll
      for (int ni = 0; ni < 4; ++ni)
        acc[mi][ni] = __builtin_amdgcn_mfma_f32_16x16x32_bf16(af[mi], bfr[ni], acc[mi][ni], 0, 0, 0);
  }

  const int row0 = m0 + wm * 32;
  const int col0 = n0 + wn * 64;
#pragma unroll
  for (int mi = 0; mi < 2; ++mi) {
#pragma unroll
    for (int ni = 0; ni < 4; ++ni) {
      const int col = col0 + ni * 16 + l15;
      const float bb = bias[col];
#pragma unroll
      for (int r = 0; r < 4; ++r) {
        const int row = row0 + mi * 16 + quad * 4 + r;
        Cout[(size_t)row * 1024 + col] = acc[mi][ni][r] + bb;
      }
    }
  }
}

// ------------------------------------------------------------- attention ----
// Block = (bh, 128 q rows), 4 waves x 32 q each (2 groups of 16).
// Grid (64 bh, 16 qtile): XCD = bh&7 -> K/V L2-resident per XCD (R7:
// FETCH 139->43 MB). Per K-tile: S^T = K.Q^T (K-frags via permutation pi),
// p = exp2(s) packed by pk2fast -> PV A-frags in regs; l via MFMA vs ones.
// Register note: plain launch_bounds(256) — a min-waves clause clamps the
// unified VGPR file and spills (R4).
__global__ __launch_bounds__(256)
void k_attn(const u16* __restrict__ qkv, const u16* __restrict__ vtg,
            u16* __restrict__ mh) {
  __shared__ __align__(16) u16 smem[16384];
  u16* const Klds = smem;          // 128 keys x 8 chunks(8 u16), chunk-swizzled
  u16* const Vlds = smem + 8192;   // 64 e x 16 chunks, chunk-swizzled

  const int t = threadIdx.x;
  const int lane = t & 63;
  const int w = t >> 6;
  const int l15 = lane & 15;
  const int quad = lane >> 4;
  const int bh = blockIdx.x, b = bh >> 4, h = bh & 15;
  const int s0 = blockIdx.y << 7;   // 128 q rows per block

  // K staging base (r=0): lam0 = t>>3 in [0,32), key0 = pi(lam0) (bits 5,6 = 0)
  const int lam0 = t >> 3;
  const int key0 = (lam0 & 3) | (((lam0 >> 2) & 3) << 3) | (((lam0 >> 4) & 1) << 2);
  const int ck = (t & 7) ^ (lam0 & 7);
  const u16* kbase = qkv + (size_t)(b * 2048 + key0) * 2048 + 1024 + h * 64 + ck * 8;
  // V staging base (r=0): e0 = t>>4 in [0,16), chunk = (t&15) ^ e0
  const int e0 = t >> 4;
  const int cv = (t & 15) ^ e0;
  const u16* vbase = vtg + ((size_t)bh * 64 + e0) * 2048 + cv * 8;
  u16* const KldsW = Klds + w * 512;
  u16* const VldsW = Vlds + w * 512;

  // Q frags (B-operand) direct from global: q = w*32 + g*16 + l15
  bf16x8 aq[2][2];
#pragma unroll
  for (int g = 0; g < 2; ++g)
#pragma unroll
    for (int ks2 = 0; ks2 < 2; ++ks2)
      aq[g][ks2] = *(const bf16x8*)(qkv +
          (size_t)(b * 2048 + s0 + w * 32 + g * 16 + l15) * 2048 +
          h * 64 + ks2 * 32 + quad * 8);

  // all-ones B-frag for the l-MFMA (bf16 1.0 = 0x3F80)
  const u32x4 onesu = (u32x4){0x3F803F80u, 0x3F803F80u, 0x3F803F80u, 0x3F803F80u};
  const bf16x8 ones = __builtin_bit_cast(bf16x8, onesu);
  const f32x4 zf = (f32x4){0.f, 0.f, 0.f, 0.f};

  f32x4 o[2][4];
  f32x4 lacc[2];
#pragma unroll
  for (int g = 0; g < 2; ++g) {
    lacc[g] = zf;
#pragma unroll
    for (int ne = 0; ne < 4; ++ne) o[g][ne] = zf;
  }

  for (int kt = 0; kt < 16; ++kt) {
    __syncthreads();  // prior tile reads done
#pragma unroll
    for (int r = 0; r < 4; ++r)
      async16(kbase + r * (32 * 2048), KldsW + r * 2048);
#pragma unroll
    for (int r = 0; r < 4; ++r)
      async16(vbase + r * (16 * 2048), VldsW + r * 2048);
    kbase += 128 * 2048;
    vbase += 128;
    __syncthreads();

#pragma unroll
    for (int ks = 0; ks < 4; ++ks) {
      u32x4 pf[2];  // per-g PV A-frag for key-chunk ks
#pragma unroll
      for (int h2 = 0; h2 < 2; ++h2) {
        const int kt8 = ks * 2 + h2;
        const int row = kt8 * 16 + l15;
        const bf16x8 kf0 = *(const bf16x8*)(Klds + row * 64 + ((quad) ^ (l15 & 7)) * 8);
        const bf16x8 kf1 = *(const bf16x8*)(Klds + row * 64 + ((4 + quad) ^ (l15 & 7)) * 8);
        f32x4 st[2];
#pragma unroll
        for (int g = 0; g < 2; ++g) {
          st[g] = __builtin_amdgcn_mfma_f32_16x16x32_bf16(kf0, aq[g][0], zf, 0, 0, 0);
          st[g] = __builtin_amdgcn_mfma_f32_16x16x32_bf16(kf1, aq[g][1], st[g], 0, 0, 0);
        }
#pragma unroll
        for (int g = 0; g < 2; ++g) {
          const float p0 = ex2(st[g][0]), p1 = ex2(st[g][1]);
          const float p2 = ex2(st[g][2]), p3 = ex2(st[g][3]);
          pf[g][h2 * 2 + 0] = pk2fast(p0, p1);
          pf[g][h2 * 2 + 1] = pk2fast(p2, p3);
        }
      }
#pragma unroll
      for (int ne = 0; ne < 4; ++ne) {
        const int e = ne * 16 + l15;
        const bf16x8 bv8 = *(const bf16x8*)(Vlds + e * 128 + (((ks * 4 + quad) ^ l15) & 15) * 8);
#pragma unroll
        for (int g = 0; g < 2; ++g)
          o[g][ne] = __builtin_amdgcn_mfma_f32_16x16x32_bf16(
              __builtin_bit_cast(bf16x8, pf[g]), bv8, o[g][ne], 0, 0, 0);
      }
#pragma unroll
      for (int g = 0; g < 2; ++g)
        lacc[g] = __builtin_amdgcn_mfma_f32_16x16x32_bf16(
            __builtin_bit_cast(bf16x8, pf[g]), ones, lacc[g], 0, 0, 0);
    }
  }

  // epilogue: O row = quad*4+r; lacc has the SAME row layout.
#pragma unroll
  for (int g = 0; g < 2; ++g) {
#pragma unroll
    for (int r = 0; r < 4; ++r) {
      const float iv = 1.f / lacc[g][r];
      const int row = s0 + w * 32 + g * 16 + quad * 4 + r;
#pragma unroll
      for (int ne = 0; ne < 4; ++ne) {
        const int col = h * 64 + ne * 16 + l15;
        mh[(size_t)(b * 2048 + row) * 1024 + col] = f2bf(o[g][ne][r] * iv);
      }
    }
  }
}

// ---------------------------------------------------------------- launch ----
extern "C" void kernel_launch(void* const* d_in, const int* in_sizes, int n_in,
                              void* d_out, int out_size, void* d_ws, size_t ws_size,
                              hipStream_t stream) {
  (void)in_sizes; (void)n_in; (void)out_size; (void)ws_size;
  const float* x  = (const float*)d_in[0];
  const float* Wq = (const float*)d_in[1];
  const float* bq = (const float*)d_in[2];
  const float* Wk = (const float*)d_in[3];
  const float* bk = (const float*)d_in[4];
  const float* Wv = (const float*)d_in[5];
  const float* bv = (const float*)d_in[6];
  const float* Wo = (const float*)d_in[7];
  const float* bo = (const float*)d_in[8];

  char* ws = (char*)d_ws;
  u16*   Xb   = (u16*)  (ws + 0);          // 16777216
  u16*   Wt   = (u16*)  (ws + 16777216);   //  6291456
  float* bqkv = (float*)(ws + 23068672);   //    12288
  u16*   Wot  = (u16*)  (ws + 23080960);   //  2097152
  u16*   QK   = (u16*)  (ws + 25178112);   // 33554432  [8192][2048] Q|K
  u16*   Vtg  = (u16*)  (ws + 58732544);   // 16777216  [64][64][2048]
  u16*   MH   = (u16*)  (ws + 75509760);   // 16777216  (total 92.3 MB)
  float* out  = (float*)d_out;

  k_pack_all <<<9228, 256, 0, stream>>>(x, Wq, Wk, Wv, bq, bk, bv, Wo,
                                        Xb, Wt, bqkv, Wot);
  k_gemm<0>  <<<dim3(24, 64), 256, 0, stream>>>(Xb, Wt, bqkv, (void*)QK, 2048, Vtg);
  k_attn     <<<dim3(64, 16), 256, 0, stream>>>(QK, Vtg, MH);
  k_gemm_out <<<dim3(8, 128), 256, 0, stream>>>(MH, Wot, bo, out);
}